// Round 14
// baseline (922.882 us; speedup 1.0000x reference)
//
#include <hip/hip_runtime.h>
#include <math.h>

// Problem constants
constexpr int kB   = 2;
constexpr int kF   = 257;   // FQ
constexpr int kT   = 100;
constexpr int kH   = 96;
constexpr int kS   = 8;
constexpr int kD   = 192;   // DIN
constexpr int kN   = 16;
constexpr int kR   = 6;
constexpr int kKF  = 5;
constexpr int kKM  = 4;
constexpr int kG   = 8;     // GROUPS
constexpr int kGC  = kH / kG;        // 12
constexpr int kBM  = kB * kF;        // 514
constexpr int kROWS = kB * kF * kT;  // 51400
constexpr int kNX  = kROWS * kH;     // 4,934,400
constexpr int kNM  = kROWS * kD;     // 9,868,800
constexpr int kDBL = kR + 2 * kN;    // 38
constexpr int kDBLP = 48;            // padded

__device__ inline float wave_reduce_sum(float v) {
    for (int o = 32; o > 0; o >>= 1) v += __shfl_xor(v, o, 64);
    return v;
}
__device__ inline float silu_f(float x) { return x / (1.f + __expf(-x)); }
__device__ inline float softplus_f(float x) { return x > 20.f ? x : log1pf(__expf(x)); }

// ---------------- LayerNorm over H=96, one wave per row ----------------
__global__ void ln_kernel(const float* __restrict__ in, float* __restrict__ out,
                          const float* __restrict__ g, const float* __restrict__ b,
                          int rows) {
    int wave = threadIdx.x >> 6;
    int lane = threadIdx.x & 63;
    int r = blockIdx.x * 4 + wave;
    if (r >= rows) return;
    const float* p = in + (size_t)r * kH;
    float v0 = p[lane];
    float v1 = (lane < 32) ? p[64 + lane] : 0.f;
    float s = wave_reduce_sum(v0 + v1);
    float mean = s * (1.f / 96.f);
    float d0 = v0 - mean;
    float d1 = (lane < 32) ? (v1 - mean) : 0.f;
    float vs = wave_reduce_sum(d0 * d0 + d1 * d1);
    float rstd = rsqrtf(vs * (1.f / 96.f) + 1e-5f);
    float* q = out + (size_t)r * kH;
    q[lane] = d0 * rstd * g[lane] + b[lane];
    if (lane < 32) q[64 + lane] = d1 * rstd * g[64 + lane] + b[64 + lane];
}

// ---------------- fused LN + squeeze (H->S) + SiLU ----------------
// lnf's output is consumed ONLY by squeeze; squeeze's old access was fully
// uncoalesced (lane=f, stride-9600 gathers). Wave-per-row LN keeps the
// normalized row in registers; 8 shuffle-reduce dots finish squeeze in-wave.
__global__ __launch_bounds__(256)
void lnsq_kernel(const float* __restrict__ in, float* __restrict__ s1,
                 const float* __restrict__ g, const float* __restrict__ b,
                 const float* __restrict__ sqw, const float* __restrict__ sqb) {
    __shared__ float sws[kS * kH];  // 768 floats
    int tid = threadIdx.x;
    for (int i = tid; i < kS * kH; i += 256) sws[i] = sqw[i];
    __syncthreads();
    int wave = tid >> 6, lane = tid & 63;
    int r = blockIdx.x * 4 + wave;
    if (r >= kROWS) return;
    int b_ = r / (kF * kT);
    int rem = r - b_ * kF * kT;
    int f = rem / kT;
    int t = rem - f * kT;
    const float* p = in + (size_t)r * kH;
    float v0 = p[lane];
    float v1 = (lane < 32) ? p[64 + lane] : 0.f;
    float s = wave_reduce_sum(v0 + v1);
    float mean = s * (1.f / 96.f);
    float d0 = v0 - mean;
    float d1 = (lane < 32) ? (v1 - mean) : 0.f;
    float vs = wave_reduce_sum(d0 * d0 + d1 * d1);
    float rstd = rsqrtf(vs * (1.f / 96.f) + 1e-5f);
    float n0 = d0 * rstd * g[lane] + b[lane];
    float n1 = 0.f;
    if (lane < 32) n1 = d1 * rstd * g[64 + lane] + b[64 + lane];
    int bt = b_ * kT + t;
    #pragma unroll
    for (int sq = 0; sq < kS; sq++) {
        float part = n0 * sws[sq * kH + lane]
                   + ((lane < 32) ? n1 * sws[sq * kH + 64 + lane] : 0.f);
        part = wave_reduce_sum(part);
        if (lane == 0)
            s1[((size_t)bt * kS + sq) * kF + f] = silu_f(part + sqb[sq]);
    }
}

// ---------------- fused unsqueeze (S->H) + SiLU + residual + LN ----------------
// Writes BOTH the residual-updated x (xout) and its LayerNorm (lnout, input
// to the stage-3 fconv). Removes one full 40MB pass + a dispatch.
__global__ __launch_bounds__(256)
void unsq_ln_kernel(const float* __restrict__ s2, float* __restrict__ x,
                    const float* __restrict__ uw, const float* __restrict__ ub,
                    const float* __restrict__ g2, const float* __restrict__ b2,
                    float* __restrict__ lnout) {
    __shared__ float uws[kH * kS];  // 768
    int tid = threadIdx.x;
    for (int i = tid; i < kH * kS; i += 256) uws[i] = uw[i];
    __syncthreads();
    int wave = tid >> 6, lane = tid & 63;
    int r = blockIdx.x * 4 + wave;
    if (r >= kROWS) return;
    int b_ = r / (kF * kT);
    int rem = r - b_ * kF * kT;
    int f = rem / kT;
    int t = rem - f * kT;
    int bt = b_ * kT + t;
    float sv[kS];
    #pragma unroll
    for (int sq = 0; sq < kS; sq++)
        sv[sq] = s2[((size_t)bt * kS + sq) * kF + f];
    float* xr = x + (size_t)r * kH;
    int h0 = lane, h1 = 64 + lane;
    float acc0 = ub[h0];
    #pragma unroll
    for (int sq = 0; sq < kS; sq++) acc0 += sv[sq] * uws[h0 * kS + sq];
    float x0 = xr[h0] + silu_f(acc0);
    float x1 = 0.f;
    if (lane < 32) {
        float acc1 = ub[h1];
        #pragma unroll
        for (int sq = 0; sq < kS; sq++) acc1 += sv[sq] * uws[h1 * kS + sq];
        x1 = xr[h1] + silu_f(acc1);
    }
    xr[h0] = x0;
    if (lane < 32) xr[h1] = x1;
    // LN of the fresh row
    float s = wave_reduce_sum(x0 + x1);
    float mean = s * (1.f / 96.f);
    float d0 = x0 - mean;
    float d1 = (lane < 32) ? (x1 - mean) : 0.f;
    float vs = wave_reduce_sum(d0 * d0 + d1 * d1);
    float rstd = rsqrtf(vs * (1.f / 96.f) + 1e-5f);
    float* q = lnout + (size_t)r * kH;
    q[h0] = d0 * rstd * g2[h0] + b2[h0];
    if (lane < 32) q[h1] = d1 * rstd * g2[h1] + b2[h1];
}

// ---------------- freq-conv stage ----------------
#define FDOT(S,K) \
  acc += xw[S][0].x*wr[K][0] + xw[S][0].y*wr[K][1] + xw[S][0].z*wr[K][2] + xw[S][0].w*wr[K][3] \
       + xw[S][1].x*wr[K][4] + xw[S][1].y*wr[K][5] + xw[S][1].z*wr[K][6] + xw[S][1].w*wr[K][7] \
       + xw[S][2].x*wr[K][8] + xw[S][2].y*wr[K][9] + xw[S][2].z*wr[K][10]+ xw[S][2].w*wr[K][11];

#define FSTEP(S0,S1,S2,S3,S4)                                              \
  if (f < fmax) {                                                          \
    const float4* cp = (const float4*)(Xs + (f + 4) * 12);                 \
    xw[S4][0] = cp[0]; xw[S4][1] = cp[1]; xw[S4][2] = cp[2];               \
    float acc = bias;                                                      \
    FDOT(S0,0) FDOT(S1,1) FDOT(S2,2) FDOT(S3,3) FDOT(S4,4)                 \
    float yv = acc > 0.f ? acc : alpha_h * acc;                            \
    size_t oi = ((size_t)(bb * kF + f) * kT + tt) * kH + g12 + hh;         \
    out[oi] = resid[oi] + yv;                                              \
    f++;                                                                   \
  }

__global__ __launch_bounds__(256)
void fconv_kernel(const float* __restrict__ ln, const float* __restrict__ resid,
                  float* __restrict__ out, const float* __restrict__ w,
                  const float* __restrict__ cb, const float* __restrict__ alpha) {
    __shared__ float Xs[261 * 12];
    __shared__ float Ws[kGC * kKF * 12];  // 720
    int g = blockIdx.x, tt = blockIdx.y, bb = blockIdx.z;
    int g12 = g * 12;
    int tid = threadIdx.x;

    for (int i = tid; i < 720; i += 256) Ws[i] = w[g * 720 + i];
    for (int i = tid; i < 257 * 12; i += 256) {
        int fs = i / 12, ci = i - fs * 12;
        Xs[(fs + 2) * 12 + ci] = ln[((size_t)(bb * kF + fs) * kT + tt) * kH + g12 + ci];
    }
    if (tid < 48) {
        const int padr[4] = {0, 1, 259, 260};
        Xs[padr[tid / 12] * 12 + (tid % 12)] = 0.f;
    }
    __syncthreads();

    int lane = tid & 63, wave = tid >> 6;
    int hh = lane % 12, fi = lane / 12;
    if (fi >= 5) return;                      // duplicate-slot lanes must retire (in-place race)
    int slot = wave * 5 + fi;
    int f0 = slot * 13;
    int fmax = min(f0 + 13, kF);

    float wr[5][12];
    #pragma unroll
    for (int k = 0; k < 5; k++)
        #pragma unroll
        for (int ci = 0; ci < 12; ci++)
            wr[k][ci] = Ws[hh * 60 + ci * 5 + k];

    float bias = cb[g12 + hh];
    float alpha_h = alpha[g12 + hh];

    float4 xw[5][3];
    #pragma unroll
    for (int s = 0; s < 4; s++) {
        int row = min(f0 + s, 260);
        const float4* cp = (const float4*)(Xs + row * 12);
        xw[s][0] = cp[0]; xw[s][1] = cp[1]; xw[s][2] = cp[2];
    }
    int f = f0;
    for (int rep = 0; rep < 3; rep++) {
        FSTEP(0,1,2,3,4)
        FSTEP(1,2,3,4,0)
        FSTEP(2,3,4,0,1)
        FSTEP(3,4,0,1,2)
        FSTEP(4,0,1,2,3)
    }
}

// ---------------- full stage: per-group GEMM over F ----------------
__global__ __launch_bounds__(256)
void fullmat_gemm(const float* __restrict__ s1, float* __restrict__ s2,
                  const float* __restrict__ fw, const float* __restrict__ fb) {
    __shared__ float As[64 * 64];  // [fk][bt]
    __shared__ float Bs[64 * 64];  // [fk][k]
    int k0 = blockIdx.x * 64, bt0 = blockIdx.y * 64, g = blockIdx.z;
    int tid = threadIdx.x;
    int rt = tid >> 4, ct = tid & 15;
    float acc[4][4];
    #pragma unroll
    for (int i = 0; i < 4; i++)
        #pragma unroll
        for (int j = 0; j < 4; j++) acc[i][j] = 0.f;

    for (int f0 = 0; f0 < kF; f0 += 64) {
        int fcnt = min(64, kF - f0);
        for (int i = tid; i < 64 * 64; i += 256) {
            int m = i & 63, fk = i >> 6;
            int bt = bt0 + m, f = f0 + fk;
            As[fk * 64 + m] = (bt < kB * kT && f < kF)
                ? s1[((size_t)bt * kS + g) * kF + f] : 0.f;
            int k = k0 + m;
            Bs[fk * 64 + m] = (k < kF && f < kF)
                ? fw[(size_t)g * kF * kF + (size_t)k * kF + f] : 0.f;
        }
        __syncthreads();
        for (int f = 0; f < fcnt; f++) {
            float4 a4 = *(const float4*)&As[f * 64 + rt * 4];
            float4 b4 = *(const float4*)&Bs[f * 64 + ct * 4];
            float ar[4] = {a4.x, a4.y, a4.z, a4.w};
            float br[4] = {b4.x, b4.y, b4.z, b4.w};
            #pragma unroll
            for (int i = 0; i < 4; i++)
                #pragma unroll
                for (int j = 0; j < 4; j++) acc[i][j] += ar[i] * br[j];
        }
        __syncthreads();
    }
    #pragma unroll
    for (int i = 0; i < 4; i++) {
        int bt = bt0 + rt * 4 + i;
        if (bt >= kB * kT) continue;
        #pragma unroll
        for (int j = 0; j < 4; j++) {
            int k = k0 + ct * 4 + j;
            if (k >= kF) continue;
            s2[((size_t)bt * kS + g) * kF + k] = acc[i][j] + fb[g * kF + k];
        }
    }
}

// ---------------- small weight transpose ----------------
__global__ void transpose_kernel(const float* __restrict__ in, float* __restrict__ out,
                                 int rows, int cols) {
    int idx = blockIdx.x * blockDim.x + threadIdx.x;
    if (idx >= rows * cols) return;
    int r = idx / cols, c = idx % cols;
    out[c * rows + r] = in[idx];
}

// xp_w [38][192] -> padded transpose wpx [192][48] (cols >=38 zero)
__global__ void xppad_kernel(const float* __restrict__ w, float* __restrict__ wp) {
    int i = blockIdx.x * 256 + threadIdx.x;
    if (i >= kD * kDBLP) return;
    int d = i / kDBLP, n = i % kDBLP;
    wp[i] = (n < kDBL) ? w[n * kD + d] : 0.f;
}

// ---------------- mamba in-proj GEMM: [51400x96] @ [96x384] ----------------
__global__ __launch_bounds__(256)
void inproj_gemm(const float* __restrict__ xn, const float* __restrict__ wT,
                 float* __restrict__ xin, float* __restrict__ z) {
    __shared__ float Al[64 * 96];  // 24.6 KB
    int r0 = blockIdx.x * 64;
    int c0 = blockIdx.y * 128;
    int tid = threadIdx.x;
    for (int i = tid; i < 64 * 24; i += 256) {
        int rr = i / 24, cq = i - rr * 24;
        int r = r0 + rr; if (r >= kROWS) r = kROWS - 1;
        *(float4*)&Al[rr * 96 + cq * 4] = *(const float4*)&xn[(size_t)r * kH + cq * 4];
    }
    __syncthreads();
    int rt = tid >> 5, ct = tid & 31;
    const float* ap = Al + rt * 8 * 96;
    const float* bp = wT + c0 + ct * 4;
    float4 acc[8];
    #pragma unroll
    for (int i = 0; i < 8; i++) acc[i] = make_float4(0.f, 0.f, 0.f, 0.f);
    for (int h = 0; h < 96; h++) {
        float4 b = *(const float4*)&bp[(size_t)h * 384];
        #pragma unroll
        for (int i = 0; i < 8; i++) {
            float av = ap[i * 96 + h];
            acc[i].x += av * b.x; acc[i].y += av * b.y;
            acc[i].z += av * b.z; acc[i].w += av * b.w;
        }
    }
    int cbase = c0 + ct * 4;
    #pragma unroll
    for (int i = 0; i < 8; i++) {
        int r = r0 + rt * 8 + i;
        if (r >= kROWS) break;
        if (cbase < kD) *(float4*)&xin[(size_t)r * kD + cbase] = acc[i];
        else            *(float4*)&z[(size_t)r * kD + cbase - kD] = acc[i];
    }
}

// ---------------- mamba out-proj GEMM + z-gating + combine ----------------
__global__ __launch_bounds__(256)
void outproj_gemm(const float* __restrict__ ym, const float* __restrict__ zg,
                  const float* __restrict__ wpT,
                  const float* __restrict__ xres, float* __restrict__ out, int dir) {
    __shared__ float Al[64 * 192];  // 49.2 KB
    int r0 = blockIdx.x * 64;
    int tid = threadIdx.x;
    for (int i = tid; i < 64 * 48; i += 256) {
        int rr = i / 48, cq = i - rr * 48;
        int r = r0 + rr; if (r >= kROWS) r = kROWS - 1;
        size_t gidx = (size_t)r * kD + cq * 4;
        float4 a = *(const float4*)&ym[gidx];
        float4 g4 = *(const float4*)&zg[gidx];
        a.x *= silu_f(g4.x); a.y *= silu_f(g4.y);
        a.z *= silu_f(g4.z); a.w *= silu_f(g4.w);
        *(float4*)&Al[rr * 192 + cq * 4] = a;
    }
    __syncthreads();
    int rt = tid >> 5, ct = tid & 31;   // cols 3*ct .. 3*ct+2
    const float* ap = Al + rt * 8 * 192;
    const float* bp = wpT + ct * 3;
    float acc[8][3];
    #pragma unroll
    for (int i = 0; i < 8; i++) { acc[i][0] = 0.f; acc[i][1] = 0.f; acc[i][2] = 0.f; }
    for (int h = 0; h < 192; h++) {
        float b0 = bp[h * 96], b1 = bp[h * 96 + 1], b2 = bp[h * 96 + 2];
        #pragma unroll
        for (int i = 0; i < 8; i++) {
            float av = ap[i * 192 + h];
            acc[i][0] += av * b0; acc[i][1] += av * b1; acc[i][2] += av * b2;
        }
    }
    int cbase = ct * 3;
    #pragma unroll
    for (int i = 0; i < 8; i++) {
        int r = r0 + rt * 8 + i;
        if (r >= kROWS) break;
        size_t o = (size_t)r * kH + cbase;
        #pragma unroll
        for (int j = 0; j < 3; j++) {
            float base = dir ? out[o + j] : xres[o + j];
            out[o + j] = base + 0.5f * acc[i][j];
        }
    }
}

// ---------------- mamba depthwise conv over T + SiLU ----------------
__global__ void mconv_kernel(const float* __restrict__ xin, float* __restrict__ xc,
                             const float* __restrict__ cw, const float* __restrict__ cb, int dir) {
    int qid = blockIdx.x * blockDim.x + threadIdx.x;
    if (qid >= kROWS * 48) return;
    int r = qid / 48, d4 = (qid - r * 48) * 4;
    int bm = r / kT, t = r - bm * kT;
    float4 acc = make_float4(cb[d4], cb[d4 + 1], cb[d4 + 2], cb[d4 + 3]);
    #pragma unroll
    for (int k = 0; k < kKM; k++) {
        int ts = dir ? (t + 3 - k) : (t + k - 3);
        if (ts < 0 || ts >= kT) continue;
        float4 v = *(const float4*)&xin[((size_t)bm * kT + ts) * kD + d4];
        acc.x += v.x * cw[(d4 + 0) * kKM + k];
        acc.y += v.y * cw[(d4 + 1) * kKM + k];
        acc.z += v.z * cw[(d4 + 2) * kKM + k];
        acc.w += v.w * cw[(d4 + 3) * kKM + k];
    }
    float4 o = make_float4(silu_f(acc.x), silu_f(acc.y), silu_f(acc.z), silu_f(acc.w));
    *(float4*)&xc[(size_t)r * kD + d4] = o;
}

// ---------------- mamba x-proj GEMM: [51400x192] @ [192x48pad] ----------------
__global__ __launch_bounds__(256)
void xpproj_gemm(const float* __restrict__ xc, float* __restrict__ dbl,
                 const float* __restrict__ wpx) {
    __shared__ float Al[64 * 192];  // 49.2 KB
    int r0 = blockIdx.x * 64;
    int tid = threadIdx.x;
    for (int i = tid; i < 64 * 48; i += 256) {
        int rr = i / 48, cq = i - rr * 48;
        int r = r0 + rr; if (r >= kROWS) r = kROWS - 1;
        *(float4*)&Al[rr * 192 + cq * 4] = *(const float4*)&xc[(size_t)r * kD + cq * 4];
    }
    __syncthreads();
    int rt = tid >> 5, ct = tid & 31;
    if (ct >= 24) return;               // 48 cols / 2 per thread
    const float* ap = Al + rt * 8 * 192;
    const float* bp = wpx + ct * 2;
    float acc[8][2];
    #pragma unroll
    for (int i = 0; i < 8; i++) { acc[i][0] = 0.f; acc[i][1] = 0.f; }
    for (int h = 0; h < 192; h++) {
        float b0 = bp[h * kDBLP], b1 = bp[h * kDBLP + 1];
        #pragma unroll
        for (int i = 0; i < 8; i++) {
            float av = ap[i * 192 + h];
            acc[i][0] += av * b0; acc[i][1] += av * b1;
        }
    }
    int cbase = ct * 2;
    #pragma unroll
    for (int i = 0; i < 8; i++) {
        int r = r0 + rt * 8 + i;
        if (r >= kROWS) break;
        #pragma unroll
        for (int j = 0; j < 2; j++) {
            int c = cbase + j;
            if (c < kDBL) dbl[(size_t)r * kDBL + c] = acc[i][j];
        }
    }
}

// ---------------- mamba selective scan v9: v8 + exp2 prescale ----------------
// A2[n] = A[n]*log2(e) so the per-step decay is exp2f(dt*A2[n]) (v_exp_f32
// natively computes 2^x) -- drops 16 v_mul per t-step vs __expf.
__global__ __launch_bounds__(192)
void scan2_kernel(const float* __restrict__ dbl0, const float* __restrict__ dbl1,
                  float* __restrict__ xc0, float* __restrict__ xc1,
                  const float* __restrict__ Al0, const float* __restrict__ Al1,
                  const float* __restrict__ dtw0, const float* __restrict__ dtw1,
                  const float* __restrict__ dtb0, const float* __restrict__ dtb1,
                  const float* __restrict__ Dp0, const float* __restrict__ Dp1,
                  int dirbase) {
    __shared__ float dsg[kT * 40];      // 16 KB
    int dd = blockIdx.y;
    int dir = dirbase + dd;
    const float* dbl   = dd ? dbl1 : dbl0;
    float* xcy         = dd ? xc1  : xc0;
    const float* A_log = dd ? Al1  : Al0;
    const float* dtw   = dd ? dtw1 : dtw0;
    const float* dtb   = dd ? dtb1 : dtb0;
    const float* Dp    = dd ? Dp1  : Dp0;

    int bm = blockIdx.x;
    int d = threadIdx.x;

    const float* drow = dbl + (size_t)bm * kT * kDBL;
    for (int i = d; i < kT * kDBL; i += 192) {
        int t = i / kDBL, j = i - t * kDBL;
        int slot = (j < 6) ? j : (j + 2);
        dsg[t * 40 + slot] = drow[i];
    }
    __syncthreads();

    constexpr float kLog2e = 1.44269504088896f;
    float A2[kN], h[kN], dw[kR];
    #pragma unroll
    for (int n = 0; n < kN; n++) { A2[n] = -__expf(A_log[d * kN + n]) * kLog2e; h[n] = 0.f; }
    #pragma unroll
    for (int j = 0; j < kR; j++) dw[j] = dtw[d * kR + j];
    float db = dtb[d], Dv = Dp[d];

    float* xrow = xcy + (size_t)bm * kT * kD + d;

    for (int tb = 0; tb < kT; tb += 4) {
        int ts[4];
        float xv[4];
        #pragma unroll
        for (int u = 0; u < 4; u++) {
            ts[u] = dir ? (kT - 1 - (tb + u)) : (tb + u);
            xv[u] = xrow[(size_t)ts[u] * kD];
        }
        #pragma unroll
        for (int u = 0; u < 4; u++) {
            const float* row = dsg + ts[u] * 40;
            float4 q0 = *(const float4*)(row);
            float4 q1 = *(const float4*)(row + 4);
            float s = db + q0.x * dw[0] + q0.y * dw[1] + q0.z * dw[2]
                         + q0.w * dw[3] + q1.x * dw[4] + q1.y * dw[5];
            float dt = softplus_f(s);
            float dtx = dt * xv[u];
            float4 B0 = *(const float4*)(row + 8);
            float4 B1 = *(const float4*)(row + 12);
            float4 B2 = *(const float4*)(row + 16);
            float4 B3 = *(const float4*)(row + 20);
            float4 C0 = *(const float4*)(row + 24);
            float4 C1 = *(const float4*)(row + 28);
            float4 C2 = *(const float4*)(row + 32);
            float4 C3 = *(const float4*)(row + 36);
            float y = 0.f;
            h[0]  = exp2f(dt * A2[0])  * h[0]  + dtx * B0.x;  y += h[0]  * C0.x;
            h[1]  = exp2f(dt * A2[1])  * h[1]  + dtx * B0.y;  y += h[1]  * C0.y;
            h[2]  = exp2f(dt * A2[2])  * h[2]  + dtx * B0.z;  y += h[2]  * C0.z;
            h[3]  = exp2f(dt * A2[3])  * h[3]  + dtx * B0.w;  y += h[3]  * C0.w;
            h[4]  = exp2f(dt * A2[4])  * h[4]  + dtx * B1.x;  y += h[4]  * C1.x;
            h[5]  = exp2f(dt * A2[5])  * h[5]  + dtx * B1.y;  y += h[5]  * C1.y;
            h[6]  = exp2f(dt * A2[6])  * h[6]  + dtx * B1.z;  y += h[6]  * C1.z;
            h[7]  = exp2f(dt * A2[7])  * h[7]  + dtx * B1.w;  y += h[7]  * C1.w;
            h[8]  = exp2f(dt * A2[8])  * h[8]  + dtx * B2.x;  y += h[8]  * C2.x;
            h[9]  = exp2f(dt * A2[9])  * h[9]  + dtx * B2.y;  y += h[9]  * C2.y;
            h[10] = exp2f(dt * A2[10]) * h[10] + dtx * B2.z;  y += h[10] * C2.z;
            h[11] = exp2f(dt * A2[11]) * h[11] + dtx * B2.w;  y += h[11] * C2.w;
            h[12] = exp2f(dt * A2[12]) * h[12] + dtx * B3.x;  y += h[12] * C3.x;
            h[13] = exp2f(dt * A2[13]) * h[13] + dtx * B3.y;  y += h[13] * C3.y;
            h[14] = exp2f(dt * A2[14]) * h[14] + dtx * B3.z;  y += h[14] * C3.z;
            h[15] = exp2f(dt * A2[15]) * h[15] + dtx * B3.w;  y += h[15] * C3.w;
            xrow[(size_t)ts[u] * kD] = y + xv[u] * Dv;
        }
    }
}

extern "C" void kernel_launch(void* const* d_in, const int* in_sizes, int n_in,
                              void* d_out, int out_size, void* d_ws, size_t ws_size,
                              hipStream_t stream) {
    const float* x       = (const float*)d_in[0];
    const float* ln1_g   = (const float*)d_in[1];
    const float* ln1_b   = (const float*)d_in[2];
    const float* conv1_w = (const float*)d_in[3];
    const float* conv1_b = (const float*)d_in[4];
    const float* prelu1  = (const float*)d_in[5];
    const float* lnf_g   = (const float*)d_in[6];
    const float* lnf_b   = (const float*)d_in[7];
    const float* sq_w    = (const float*)d_in[8];
    const float* sq_b    = (const float*)d_in[9];
    const float* full_w  = (const float*)d_in[10];
    const float* full_b  = (const float*)d_in[11];
    const float* unsq_w  = (const float*)d_in[12];
    const float* unsq_b  = (const float*)d_in[13];
    const float* ln2_g   = (const float*)d_in[14];
    const float* ln2_b   = (const float*)d_in[15];
    const float* conv2_w = (const float*)d_in[16];
    const float* conv2_b = (const float*)d_in[17];
    const float* prelu2  = (const float*)d_in[18];
    const float* lnm_g   = (const float*)d_in[19];
    const float* lnm_b   = (const float*)d_in[20];

    float* ws   = (float*)d_ws;
    float* xbuf = ws;
    float* xn   = ws + (size_t)kNX;
    float* R1   = xn + (size_t)kNX;               // kNM
    float* R2   = R1 + (size_t)kNM;               // kNM: s1 / z0
    float* R3   = R2 + (size_t)kNM;               // kNM: s2 / z1(batched) / xc(fallback)
    float* wTs  = R3 + (size_t)kNM;
    float* in_wT[2]  = { wTs, wTs + 2 * kD * kH };                  // [96][384]
    float* out_wp[2] = { wTs + 2 * (2 * kD * kH),
                         wTs + 2 * (2 * kD * kH) + kD * kH };       // [192][96]
    float* xp_wp[2]  = { wTs + 2 * (2 * kD * kH) + 2 * kD * kH,
                         wTs + 2 * (2 * kD * kH) + 2 * kD * kH + kD * kDBLP }; // [192][48]
    float* wEnd = wTs + 2 * (2 * kD * kH) + 2 * kD * kH + 2 * kD * kDBLP;
    float* R4 = wEnd;                             // kNM: xc0 (batched only)
    float* R5 = R4 + (size_t)kNM;                 // kNM: xc1 (batched only)
    size_t need_batched = (size_t)((R5 + (size_t)kNM) - ws) * sizeof(float);
    bool batched = (ws_size >= need_batched);

    const float* mw[2][8];
    for (int dir = 0; dir < 2; dir++) {
        int wi = 21 + dir * 9;
        mw[dir][0] = (const float*)d_in[wi + 1];  // conv_w
        mw[dir][1] = (const float*)d_in[wi + 2];  // conv_b
        mw[dir][2] = (const float*)d_in[wi + 4];  // dt_w
        mw[dir][3] = (const float*)d_in[wi + 5];  // dt_b
        mw[dir][4] = (const float*)d_in[wi + 6];  // A_log
        mw[dir][5] = (const float*)d_in[wi + 7];  // D
        transpose_kernel<<<(2 * kD * kH + 255) / 256, 256, 0, stream>>>(
            (const float*)d_in[wi + 0], in_wT[dir], 2 * kD, kH);
        transpose_kernel<<<(kH * kD + 255) / 256, 256, 0, stream>>>(
            (const float*)d_in[wi + 8], out_wp[dir], kH, kD);
        xppad_kernel<<<(kD * kDBLP + 255) / 256, 256, 0, stream>>>(
            (const float*)d_in[wi + 3], xp_wp[dir]);
    }

    int lnGrid = (kROWS + 3) / 4;
    dim3 fcGrid(kG, kT, kB);
    int gemmGrid = (kROWS + 63) / 64;
    int mcGrid = (kROWS * 48 + 255) / 256;

    // stage 1: x = x + fconv(x)
    ln_kernel<<<lnGrid, 256, 0, stream>>>(x, R1, ln1_g, ln1_b, kROWS);
    fconv_kernel<<<fcGrid, 256, 0, stream>>>(R1, x, xbuf, conv1_w, conv1_b, prelu1);

    // stage 2: x = x + full(x)   [lnf+squeeze fused; unsqueeze+ln2 fused]
    lnsq_kernel<<<lnGrid, 256, 0, stream>>>(xbuf, R2, lnf_g, lnf_b, sq_w, sq_b);
    fullmat_gemm<<<dim3(5, 4, kS), 256, 0, stream>>>(R2, R3, full_w, full_b);
    unsq_ln_kernel<<<lnGrid, 256, 0, stream>>>(R3, xbuf, unsq_w, unsq_b, ln2_g, ln2_b, R1);

    // stage 3: x = x + fconv(x)  (in-place: resid == out; R1 holds ln2 out)
    fconv_kernel<<<fcGrid, 256, 0, stream>>>(R1, xbuf, xbuf, conv2_w, conv2_b, prelu2);

    // mamba input: xn = LN(x)
    ln_kernel<<<lnGrid, 256, 0, stream>>>(xbuf, xn, lnm_g, lnm_b, kROWS);

    if (batched) {
        float* dbl0 = xn;                                  // xn dead after inprojs
        float* dbl1 = xn + (size_t)kROWS * kDBL;
        inproj_gemm<<<dim3(gemmGrid, 3), 256, 0, stream>>>(xn, in_wT[0], R1, R2);
        mconv_kernel<<<mcGrid, 256, 0, stream>>>(R1, R4, mw[0][0], mw[0][1], 0);
        inproj_gemm<<<dim3(gemmGrid, 3), 256, 0, stream>>>(xn, in_wT[1], R1, R3);
        mconv_kernel<<<mcGrid, 256, 0, stream>>>(R1, R5, mw[1][0], mw[1][1], 1);
        xpproj_gemm<<<gemmGrid, 256, 0, stream>>>(R4, dbl0, xp_wp[0]);
        xpproj_gemm<<<gemmGrid, 256, 0, stream>>>(R5, dbl1, xp_wp[1]);
        scan2_kernel<<<dim3(kBM, 2), 192, 0, stream>>>(
            dbl0, dbl1, R4, R5,
            mw[0][4], mw[1][4], mw[0][2], mw[1][2],
            mw[0][3], mw[1][3], mw[0][5], mw[1][5], 0);
        outproj_gemm<<<gemmGrid, 256, 0, stream>>>(R4, R2, out_wp[0], xbuf, (float*)d_out, 0);
        outproj_gemm<<<gemmGrid, 256, 0, stream>>>(R5, R3, out_wp[1], xbuf, (float*)d_out, 1);
    } else {
        for (int dir = 0; dir < 2; dir++) {
            inproj_gemm<<<dim3(gemmGrid, 3), 256, 0, stream>>>(xn, in_wT[dir], R1, R2);
            mconv_kernel<<<mcGrid, 256, 0, stream>>>(R1, R3, mw[dir][0], mw[dir][1], dir);
            xpproj_gemm<<<gemmGrid, 256, 0, stream>>>(R3, R1, xp_wp[dir]);
            scan2_kernel<<<dim3(kBM, 1), 192, 0, stream>>>(
                R1, R1, R3, R3,
                mw[dir][4], mw[dir][4], mw[dir][2], mw[dir][2],
                mw[dir][3], mw[dir][3], mw[dir][5], mw[dir][5], dir);
            outproj_gemm<<<gemmGrid, 256, 0, stream>>>(R3, R2, out_wp[dir], xbuf, (float*)d_out, dir);
        }
    }
}

// Round 15
// 894.853 us; speedup vs baseline: 1.0313x; 1.0313x over previous
//
#include <hip/hip_runtime.h>
#include <math.h>

// Problem constants
constexpr int kB   = 2;
constexpr int kF   = 257;   // FQ
constexpr int kT   = 100;
constexpr int kH   = 96;
constexpr int kS   = 8;
constexpr int kD   = 192;   // DIN
constexpr int kN   = 16;
constexpr int kR   = 6;
constexpr int kKF  = 5;
constexpr int kKM  = 4;
constexpr int kG   = 8;     // GROUPS
constexpr int kGC  = kH / kG;        // 12
constexpr int kBM  = kB * kF;        // 514
constexpr int kROWS = kB * kF * kT;  // 51400
constexpr int kNX  = kROWS * kH;     // 4,934,400
constexpr int kNM  = kROWS * kD;     // 9,868,800
constexpr int kDBL = kR + 2 * kN;    // 38
constexpr int kDBLP = 48;            // padded

__device__ inline float wave_reduce_sum(float v) {
    for (int o = 32; o > 0; o >>= 1) v += __shfl_xor(v, o, 64);
    return v;
}
__device__ inline float silu_f(float x) { return x / (1.f + __expf(-x)); }
__device__ inline float softplus_f(float x) { return x > 20.f ? x : log1pf(__expf(x)); }

// ---------------- LayerNorm over H=96, one wave per row ----------------
__global__ void ln_kernel(const float* __restrict__ in, float* __restrict__ out,
                          const float* __restrict__ g, const float* __restrict__ b,
                          int rows) {
    int wave = threadIdx.x >> 6;
    int lane = threadIdx.x & 63;
    int r = blockIdx.x * 4 + wave;
    if (r >= rows) return;
    const float* p = in + (size_t)r * kH;
    float v0 = p[lane];
    float v1 = (lane < 32) ? p[64 + lane] : 0.f;
    float s = wave_reduce_sum(v0 + v1);
    float mean = s * (1.f / 96.f);
    float d0 = v0 - mean;
    float d1 = (lane < 32) ? (v1 - mean) : 0.f;
    float vs = wave_reduce_sum(d0 * d0 + d1 * d1);
    float rstd = rsqrtf(vs * (1.f / 96.f) + 1e-5f);
    float* q = out + (size_t)r * kH;
    q[lane] = d0 * rstd * g[lane] + b[lane];
    if (lane < 32) q[64 + lane] = d1 * rstd * g[64 + lane] + b[64 + lane];
}

// ---------------- fused LN + squeeze (H->S) + SiLU ----------------
__global__ __launch_bounds__(256)
void lnsq_kernel(const float* __restrict__ in, float* __restrict__ s1,
                 const float* __restrict__ g, const float* __restrict__ b,
                 const float* __restrict__ sqw, const float* __restrict__ sqb) {
    __shared__ float sws[kS * kH];  // 768 floats
    int tid = threadIdx.x;
    for (int i = tid; i < kS * kH; i += 256) sws[i] = sqw[i];
    __syncthreads();
    int wave = tid >> 6, lane = tid & 63;
    int r = blockIdx.x * 4 + wave;
    if (r >= kROWS) return;
    int b_ = r / (kF * kT);
    int rem = r - b_ * kF * kT;
    int f = rem / kT;
    int t = rem - f * kT;
    const float* p = in + (size_t)r * kH;
    float v0 = p[lane];
    float v1 = (lane < 32) ? p[64 + lane] : 0.f;
    float s = wave_reduce_sum(v0 + v1);
    float mean = s * (1.f / 96.f);
    float d0 = v0 - mean;
    float d1 = (lane < 32) ? (v1 - mean) : 0.f;
    float vs = wave_reduce_sum(d0 * d0 + d1 * d1);
    float rstd = rsqrtf(vs * (1.f / 96.f) + 1e-5f);
    float n0 = d0 * rstd * g[lane] + b[lane];
    float n1 = 0.f;
    if (lane < 32) n1 = d1 * rstd * g[64 + lane] + b[64 + lane];
    int bt = b_ * kT + t;
    #pragma unroll
    for (int sq = 0; sq < kS; sq++) {
        float part = n0 * sws[sq * kH + lane]
                   + ((lane < 32) ? n1 * sws[sq * kH + 64 + lane] : 0.f);
        part = wave_reduce_sum(part);
        if (lane == 0)
            s1[((size_t)bt * kS + sq) * kF + f] = silu_f(part + sqb[sq]);
    }
}

// ---------------- fused unsqueeze (S->H) + SiLU + residual + LN ----------------
__global__ __launch_bounds__(256)
void unsq_ln_kernel(const float* __restrict__ s2, float* __restrict__ x,
                    const float* __restrict__ uw, const float* __restrict__ ub,
                    const float* __restrict__ g2, const float* __restrict__ b2,
                    float* __restrict__ lnout) {
    __shared__ float uws[kH * kS];  // 768
    int tid = threadIdx.x;
    for (int i = tid; i < kH * kS; i += 256) uws[i] = uw[i];
    __syncthreads();
    int wave = tid >> 6, lane = tid & 63;
    int r = blockIdx.x * 4 + wave;
    if (r >= kROWS) return;
    int b_ = r / (kF * kT);
    int rem = r - b_ * kF * kT;
    int f = rem / kT;
    int t = rem - f * kT;
    int bt = b_ * kT + t;
    float sv[kS];
    #pragma unroll
    for (int sq = 0; sq < kS; sq++)
        sv[sq] = s2[((size_t)bt * kS + sq) * kF + f];
    float* xr = x + (size_t)r * kH;
    int h0 = lane, h1 = 64 + lane;
    float acc0 = ub[h0];
    #pragma unroll
    for (int sq = 0; sq < kS; sq++) acc0 += sv[sq] * uws[h0 * kS + sq];
    float x0 = xr[h0] + silu_f(acc0);
    float x1 = 0.f;
    if (lane < 32) {
        float acc1 = ub[h1];
        #pragma unroll
        for (int sq = 0; sq < kS; sq++) acc1 += sv[sq] * uws[h1 * kS + sq];
        x1 = xr[h1] + silu_f(acc1);
    }
    xr[h0] = x0;
    if (lane < 32) xr[h1] = x1;
    // LN of the fresh row
    float s = wave_reduce_sum(x0 + x1);
    float mean = s * (1.f / 96.f);
    float d0 = x0 - mean;
    float d1 = (lane < 32) ? (x1 - mean) : 0.f;
    float vs = wave_reduce_sum(d0 * d0 + d1 * d1);
    float rstd = rsqrtf(vs * (1.f / 96.f) + 1e-5f);
    float* q = lnout + (size_t)r * kH;
    q[h0] = d0 * rstd * g2[h0] + b2[h0];
    if (lane < 32) q[h1] = d1 * rstd * g2[h1] + b2[h1];
}

// ---------------- freq-conv stage ----------------
#define FDOT(S,K) \
  acc += xw[S][0].x*wr[K][0] + xw[S][0].y*wr[K][1] + xw[S][0].z*wr[K][2] + xw[S][0].w*wr[K][3] \
       + xw[S][1].x*wr[K][4] + xw[S][1].y*wr[K][5] + xw[S][1].z*wr[K][6] + xw[S][1].w*wr[K][7] \
       + xw[S][2].x*wr[K][8] + xw[S][2].y*wr[K][9] + xw[S][2].z*wr[K][10]+ xw[S][2].w*wr[K][11];

#define FSTEP(S0,S1,S2,S3,S4)                                              \
  if (f < fmax) {                                                          \
    const float4* cp = (const float4*)(Xs + (f + 4) * 12);                 \
    xw[S4][0] = cp[0]; xw[S4][1] = cp[1]; xw[S4][2] = cp[2];               \
    float acc = bias;                                                      \
    FDOT(S0,0) FDOT(S1,1) FDOT(S2,2) FDOT(S3,3) FDOT(S4,4)                 \
    float yv = acc > 0.f ? acc : alpha_h * acc;                            \
    size_t oi = ((size_t)(bb * kF + f) * kT + tt) * kH + g12 + hh;         \
    out[oi] = resid[oi] + yv;                                              \
    f++;                                                                   \
  }

__global__ __launch_bounds__(256)
void fconv_kernel(const float* __restrict__ ln, const float* __restrict__ resid,
                  float* __restrict__ out, const float* __restrict__ w,
                  const float* __restrict__ cb, const float* __restrict__ alpha) {
    __shared__ float Xs[261 * 12];
    __shared__ float Ws[kGC * kKF * 12];  // 720
    int g = blockIdx.x, tt = blockIdx.y, bb = blockIdx.z;
    int g12 = g * 12;
    int tid = threadIdx.x;

    for (int i = tid; i < 720; i += 256) Ws[i] = w[g * 720 + i];
    for (int i = tid; i < 257 * 12; i += 256) {
        int fs = i / 12, ci = i - fs * 12;
        Xs[(fs + 2) * 12 + ci] = ln[((size_t)(bb * kF + fs) * kT + tt) * kH + g12 + ci];
    }
    if (tid < 48) {
        const int padr[4] = {0, 1, 259, 260};
        Xs[padr[tid / 12] * 12 + (tid % 12)] = 0.f;
    }
    __syncthreads();

    int lane = tid & 63, wave = tid >> 6;
    int hh = lane % 12, fi = lane / 12;
    if (fi >= 5) return;                      // duplicate-slot lanes must retire (in-place race)
    int slot = wave * 5 + fi;
    int f0 = slot * 13;
    int fmax = min(f0 + 13, kF);

    float wr[5][12];
    #pragma unroll
    for (int k = 0; k < 5; k++)
        #pragma unroll
        for (int ci = 0; ci < 12; ci++)
            wr[k][ci] = Ws[hh * 60 + ci * 5 + k];

    float bias = cb[g12 + hh];
    float alpha_h = alpha[g12 + hh];

    float4 xw[5][3];
    #pragma unroll
    for (int s = 0; s < 4; s++) {
        int row = min(f0 + s, 260);
        const float4* cp = (const float4*)(Xs + row * 12);
        xw[s][0] = cp[0]; xw[s][1] = cp[1]; xw[s][2] = cp[2];
    }
    int f = f0;
    for (int rep = 0; rep < 3; rep++) {
        FSTEP(0,1,2,3,4)
        FSTEP(1,2,3,4,0)
        FSTEP(2,3,4,0,1)
        FSTEP(3,4,0,1,2)
        FSTEP(4,0,1,2,3)
    }
}

// ---------------- full stage: per-group GEMM over F ----------------
__global__ __launch_bounds__(256)
void fullmat_gemm(const float* __restrict__ s1, float* __restrict__ s2,
                  const float* __restrict__ fw, const float* __restrict__ fb) {
    __shared__ float As[64 * 64];  // [fk][bt]
    __shared__ float Bs[64 * 64];  // [fk][k]
    int k0 = blockIdx.x * 64, bt0 = blockIdx.y * 64, g = blockIdx.z;
    int tid = threadIdx.x;
    int rt = tid >> 4, ct = tid & 15;
    float acc[4][4];
    #pragma unroll
    for (int i = 0; i < 4; i++)
        #pragma unroll
        for (int j = 0; j < 4; j++) acc[i][j] = 0.f;

    for (int f0 = 0; f0 < kF; f0 += 64) {
        int fcnt = min(64, kF - f0);
        for (int i = tid; i < 64 * 64; i += 256) {
            int m = i & 63, fk = i >> 6;
            int bt = bt0 + m, f = f0 + fk;
            As[fk * 64 + m] = (bt < kB * kT && f < kF)
                ? s1[((size_t)bt * kS + g) * kF + f] : 0.f;
            int k = k0 + m;
            Bs[fk * 64 + m] = (k < kF && f < kF)
                ? fw[(size_t)g * kF * kF + (size_t)k * kF + f] : 0.f;
        }
        __syncthreads();
        for (int f = 0; f < fcnt; f++) {
            float4 a4 = *(const float4*)&As[f * 64 + rt * 4];
            float4 b4 = *(const float4*)&Bs[f * 64 + ct * 4];
            float ar[4] = {a4.x, a4.y, a4.z, a4.w};
            float br[4] = {b4.x, b4.y, b4.z, b4.w};
            #pragma unroll
            for (int i = 0; i < 4; i++)
                #pragma unroll
                for (int j = 0; j < 4; j++) acc[i][j] += ar[i] * br[j];
        }
        __syncthreads();
    }
    #pragma unroll
    for (int i = 0; i < 4; i++) {
        int bt = bt0 + rt * 4 + i;
        if (bt >= kB * kT) continue;
        #pragma unroll
        for (int j = 0; j < 4; j++) {
            int k = k0 + ct * 4 + j;
            if (k >= kF) continue;
            s2[((size_t)bt * kS + g) * kF + k] = acc[i][j] + fb[g * kF + k];
        }
    }
}

// ---------------- small weight transpose ----------------
__global__ void transpose_kernel(const float* __restrict__ in, float* __restrict__ out,
                                 int rows, int cols) {
    int idx = blockIdx.x * blockDim.x + threadIdx.x;
    if (idx >= rows * cols) return;
    int r = idx / cols, c = idx % cols;
    out[c * rows + r] = in[idx];
}

// xp_w [38][192] -> padded transpose wpx [192][48] (cols >=38 zero)
__global__ void xppad_kernel(const float* __restrict__ w, float* __restrict__ wp) {
    int i = blockIdx.x * 256 + threadIdx.x;
    if (i >= kD * kDBLP) return;
    int d = i / kDBLP, n = i % kDBLP;
    wp[i] = (n < kDBL) ? w[n * kD + d] : 0.f;
}

// ---------------- mamba in-proj GEMM: [51400x96] @ [96x384] ----------------
__global__ __launch_bounds__(256)
void inproj_gemm(const float* __restrict__ xn, const float* __restrict__ wT,
                 float* __restrict__ xin, float* __restrict__ z) {
    __shared__ float Al[64 * 96];  // 24.6 KB
    int r0 = blockIdx.x * 64;
    int c0 = blockIdx.y * 128;
    int tid = threadIdx.x;
    for (int i = tid; i < 64 * 24; i += 256) {
        int rr = i / 24, cq = i - rr * 24;
        int r = r0 + rr; if (r >= kROWS) r = kROWS - 1;
        *(float4*)&Al[rr * 96 + cq * 4] = *(const float4*)&xn[(size_t)r * kH + cq * 4];
    }
    __syncthreads();
    int rt = tid >> 5, ct = tid & 31;
    const float* ap = Al + rt * 8 * 96;
    const float* bp = wT + c0 + ct * 4;
    float4 acc[8];
    #pragma unroll
    for (int i = 0; i < 8; i++) acc[i] = make_float4(0.f, 0.f, 0.f, 0.f);
    for (int h = 0; h < 96; h++) {
        float4 b = *(const float4*)&bp[(size_t)h * 384];
        #pragma unroll
        for (int i = 0; i < 8; i++) {
            float av = ap[i * 96 + h];
            acc[i].x += av * b.x; acc[i].y += av * b.y;
            acc[i].z += av * b.z; acc[i].w += av * b.w;
        }
    }
    int cbase = c0 + ct * 4;
    #pragma unroll
    for (int i = 0; i < 8; i++) {
        int r = r0 + rt * 8 + i;
        if (r >= kROWS) break;
        if (cbase < kD) *(float4*)&xin[(size_t)r * kD + cbase] = acc[i];
        else            *(float4*)&z[(size_t)r * kD + cbase - kD] = acc[i];
    }
}

// ---------------- mamba out-proj GEMM + z-gating + combine ----------------
__global__ __launch_bounds__(256)
void outproj_gemm(const float* __restrict__ ym, const float* __restrict__ zg,
                  const float* __restrict__ wpT,
                  const float* __restrict__ xres, float* __restrict__ out, int dir) {
    __shared__ float Al[64 * 192];  // 49.2 KB
    int r0 = blockIdx.x * 64;
    int tid = threadIdx.x;
    for (int i = tid; i < 64 * 48; i += 256) {
        int rr = i / 48, cq = i - rr * 48;
        int r = r0 + rr; if (r >= kROWS) r = kROWS - 1;
        size_t gidx = (size_t)r * kD + cq * 4;
        float4 a = *(const float4*)&ym[gidx];
        float4 g4 = *(const float4*)&zg[gidx];
        a.x *= silu_f(g4.x); a.y *= silu_f(g4.y);
        a.z *= silu_f(g4.z); a.w *= silu_f(g4.w);
        *(float4*)&Al[rr * 192 + cq * 4] = a;
    }
    __syncthreads();
    int rt = tid >> 5, ct = tid & 31;   // cols 3*ct .. 3*ct+2
    const float* ap = Al + rt * 8 * 192;
    const float* bp = wpT + ct * 3;
    float acc[8][3];
    #pragma unroll
    for (int i = 0; i < 8; i++) { acc[i][0] = 0.f; acc[i][1] = 0.f; acc[i][2] = 0.f; }
    for (int h = 0; h < 192; h++) {
        float b0 = bp[h * 96], b1 = bp[h * 96 + 1], b2 = bp[h * 96 + 2];
        #pragma unroll
        for (int i = 0; i < 8; i++) {
            float av = ap[i * 192 + h];
            acc[i][0] += av * b0; acc[i][1] += av * b1; acc[i][2] += av * b2;
        }
    }
    int cbase = ct * 3;
    #pragma unroll
    for (int i = 0; i < 8; i++) {
        int r = r0 + rt * 8 + i;
        if (r >= kROWS) break;
        size_t o = (size_t)r * kH + cbase;
        #pragma unroll
        for (int j = 0; j < 3; j++) {
            float base = dir ? out[o + j] : xres[o + j];
            out[o + j] = base + 0.5f * acc[i][j];
        }
    }
}

// ---------------- mamba depthwise conv over T + SiLU ----------------
__global__ void mconv_kernel(const float* __restrict__ xin, float* __restrict__ xc,
                             const float* __restrict__ cw, const float* __restrict__ cb, int dir) {
    int qid = blockIdx.x * blockDim.x + threadIdx.x;
    if (qid >= kROWS * 48) return;
    int r = qid / 48, d4 = (qid - r * 48) * 4;
    int bm = r / kT, t = r - bm * kT;
    float4 acc = make_float4(cb[d4], cb[d4 + 1], cb[d4 + 2], cb[d4 + 3]);
    #pragma unroll
    for (int k = 0; k < kKM; k++) {
        int ts = dir ? (t + 3 - k) : (t + k - 3);
        if (ts < 0 || ts >= kT) continue;
        float4 v = *(const float4*)&xin[((size_t)bm * kT + ts) * kD + d4];
        acc.x += v.x * cw[(d4 + 0) * kKM + k];
        acc.y += v.y * cw[(d4 + 1) * kKM + k];
        acc.z += v.z * cw[(d4 + 2) * kKM + k];
        acc.w += v.w * cw[(d4 + 3) * kKM + k];
    }
    float4 o = make_float4(silu_f(acc.x), silu_f(acc.y), silu_f(acc.z), silu_f(acc.w));
    *(float4*)&xc[(size_t)r * kD + d4] = o;
}

// ---------------- mamba x-proj GEMM: [51400x192] @ [192x48pad] ----------------
__global__ __launch_bounds__(256)
void xpproj_gemm(const float* __restrict__ xc, float* __restrict__ dbl,
                 const float* __restrict__ wpx) {
    __shared__ float Al[64 * 192];  // 49.2 KB
    int r0 = blockIdx.x * 64;
    int tid = threadIdx.x;
    for (int i = tid; i < 64 * 48; i += 256) {
        int rr = i / 48, cq = i - rr * 48;
        int r = r0 + rr; if (r >= kROWS) r = kROWS - 1;
        *(float4*)&Al[rr * 192 + cq * 4] = *(const float4*)&xc[(size_t)r * kD + cq * 4];
    }
    __syncthreads();
    int rt = tid >> 5, ct = tid & 31;
    if (ct >= 24) return;               // 48 cols / 2 per thread
    const float* ap = Al + rt * 8 * 192;
    const float* bp = wpx + ct * 2;
    float acc[8][2];
    #pragma unroll
    for (int i = 0; i < 8; i++) { acc[i][0] = 0.f; acc[i][1] = 0.f; }
    for (int h = 0; h < 192; h++) {
        float b0 = bp[h * kDBLP], b1 = bp[h * kDBLP + 1];
        #pragma unroll
        for (int i = 0; i < 8; i++) {
            float av = ap[i * 192 + h];
            acc[i][0] += av * b0; acc[i][1] += av * b1;
        }
    }
    int cbase = ct * 2;
    #pragma unroll
    for (int i = 0; i < 8; i++) {
        int r = r0 + rt * 8 + i;
        if (r >= kROWS) break;
        #pragma unroll
        for (int j = 0; j < 2; j++) {
            int c = cbase + j;
            if (c < kDBL) dbl[(size_t)r * kDBL + c] = acc[i][j];
        }
    }
}

// ---------------- mamba selective scan (R13 proven body: __expf) ----------------
// Thread per (bm,d); grid (514, 2 dirs), 192 threads. Per-bm dbl block staged
// once into LDS as [t][40]; 4-deep xv prefetch; z-gating lives in outproj.
// __expf (v_mul+v_exp) -- NOT exp2f (libm, range-check branches, R14 -37us lesson).
__global__ __launch_bounds__(192)
void scan2_kernel(const float* __restrict__ dbl0, const float* __restrict__ dbl1,
                  float* __restrict__ xc0, float* __restrict__ xc1,
                  const float* __restrict__ Al0, const float* __restrict__ Al1,
                  const float* __restrict__ dtw0, const float* __restrict__ dtw1,
                  const float* __restrict__ dtb0, const float* __restrict__ dtb1,
                  const float* __restrict__ Dp0, const float* __restrict__ Dp1,
                  int dirbase) {
    __shared__ float dsg[kT * 40];      // 16 KB
    int dd = blockIdx.y;
    int dir = dirbase + dd;
    const float* dbl   = dd ? dbl1 : dbl0;
    float* xcy         = dd ? xc1  : xc0;
    const float* A_log = dd ? Al1  : Al0;
    const float* dtw   = dd ? dtw1 : dtw0;
    const float* dtb   = dd ? dtb1 : dtb0;
    const float* Dp    = dd ? Dp1  : Dp0;

    int bm = blockIdx.x;
    int d = threadIdx.x;

    const float* drow = dbl + (size_t)bm * kT * kDBL;
    for (int i = d; i < kT * kDBL; i += 192) {
        int t = i / kDBL, j = i - t * kDBL;
        int slot = (j < 6) ? j : (j + 2);
        dsg[t * 40 + slot] = drow[i];
    }
    __syncthreads();

    float A[kN], h[kN], dw[kR];
    #pragma unroll
    for (int n = 0; n < kN; n++) { A[n] = -__expf(A_log[d * kN + n]); h[n] = 0.f; }
    #pragma unroll
    for (int j = 0; j < kR; j++) dw[j] = dtw[d * kR + j];
    float db = dtb[d], Dv = Dp[d];

    float* xrow = xcy + (size_t)bm * kT * kD + d;

    for (int tb = 0; tb < kT; tb += 4) {
        int ts[4];
        float xv[4];
        #pragma unroll
        for (int u = 0; u < 4; u++) {
            ts[u] = dir ? (kT - 1 - (tb + u)) : (tb + u);
            xv[u] = xrow[(size_t)ts[u] * kD];
        }
        #pragma unroll
        for (int u = 0; u < 4; u++) {
            const float* row = dsg + ts[u] * 40;
            float4 q0 = *(const float4*)(row);
            float4 q1 = *(const float4*)(row + 4);
            float s = db + q0.x * dw[0] + q0.y * dw[1] + q0.z * dw[2]
                         + q0.w * dw[3] + q1.x * dw[4] + q1.y * dw[5];
            float dt = softplus_f(s);
            float dtx = dt * xv[u];
            float4 B0 = *(const float4*)(row + 8);
            float4 B1 = *(const float4*)(row + 12);
            float4 B2 = *(const float4*)(row + 16);
            float4 B3 = *(const float4*)(row + 20);
            float4 C0 = *(const float4*)(row + 24);
            float4 C1 = *(const float4*)(row + 28);
            float4 C2 = *(const float4*)(row + 32);
            float4 C3 = *(const float4*)(row + 36);
            float y = 0.f;
            h[0]  = __expf(dt * A[0])  * h[0]  + dtx * B0.x;  y += h[0]  * C0.x;
            h[1]  = __expf(dt * A[1])  * h[1]  + dtx * B0.y;  y += h[1]  * C0.y;
            h[2]  = __expf(dt * A[2])  * h[2]  + dtx * B0.z;  y += h[2]  * C0.z;
            h[3]  = __expf(dt * A[3])  * h[3]  + dtx * B0.w;  y += h[3]  * C0.w;
            h[4]  = __expf(dt * A[4])  * h[4]  + dtx * B1.x;  y += h[4]  * C1.x;
            h[5]  = __expf(dt * A[5])  * h[5]  + dtx * B1.y;  y += h[5]  * C1.y;
            h[6]  = __expf(dt * A[6])  * h[6]  + dtx * B1.z;  y += h[6]  * C1.z;
            h[7]  = __expf(dt * A[7])  * h[7]  + dtx * B1.w;  y += h[7]  * C1.w;
            h[8]  = __expf(dt * A[8])  * h[8]  + dtx * B2.x;  y += h[8]  * C2.x;
            h[9]  = __expf(dt * A[9])  * h[9]  + dtx * B2.y;  y += h[9]  * C2.y;
            h[10] = __expf(dt * A[10]) * h[10] + dtx * B2.z;  y += h[10] * C2.z;
            h[11] = __expf(dt * A[11]) * h[11] + dtx * B2.w;  y += h[11] * C2.w;
            h[12] = __expf(dt * A[12]) * h[12] + dtx * B3.x;  y += h[12] * C3.x;
            h[13] = __expf(dt * A[13]) * h[13] + dtx * B3.y;  y += h[13] * C3.y;
            h[14] = __expf(dt * A[14]) * h[14] + dtx * B3.z;  y += h[14] * C3.z;
            h[15] = __expf(dt * A[15]) * h[15] + dtx * B3.w;  y += h[15] * C3.w;
            xrow[(size_t)ts[u] * kD] = y + xv[u] * Dv;
        }
    }
}

extern "C" void kernel_launch(void* const* d_in, const int* in_sizes, int n_in,
                              void* d_out, int out_size, void* d_ws, size_t ws_size,
                              hipStream_t stream) {
    const float* x       = (const float*)d_in[0];
    const float* ln1_g   = (const float*)d_in[1];
    const float* ln1_b   = (const float*)d_in[2];
    const float* conv1_w = (const float*)d_in[3];
    const float* conv1_b = (const float*)d_in[4];
    const float* prelu1  = (const float*)d_in[5];
    const float* lnf_g   = (const float*)d_in[6];
    const float* lnf_b   = (const float*)d_in[7];
    const float* sq_w    = (const float*)d_in[8];
    const float* sq_b    = (const float*)d_in[9];
    const float* full_w  = (const float*)d_in[10];
    const float* full_b  = (const float*)d_in[11];
    const float* unsq_w  = (const float*)d_in[12];
    const float* unsq_b  = (const float*)d_in[13];
    const float* ln2_g   = (const float*)d_in[14];
    const float* ln2_b   = (const float*)d_in[15];
    const float* conv2_w = (const float*)d_in[16];
    const float* conv2_b = (const float*)d_in[17];
    const float* prelu2  = (const float*)d_in[18];
    const float* lnm_g   = (const float*)d_in[19];
    const float* lnm_b   = (const float*)d_in[20];

    float* ws   = (float*)d_ws;
    float* xbuf = ws;
    float* xn   = ws + (size_t)kNX;
    float* R1   = xn + (size_t)kNX;               // kNM
    float* R2   = R1 + (size_t)kNM;               // kNM: s1 / z0
    float* R3   = R2 + (size_t)kNM;               // kNM: s2 / z1(batched) / xc(fallback)
    float* wTs  = R3 + (size_t)kNM;
    float* in_wT[2]  = { wTs, wTs + 2 * kD * kH };                  // [96][384]
    float* out_wp[2] = { wTs + 2 * (2 * kD * kH),
                         wTs + 2 * (2 * kD * kH) + kD * kH };       // [192][96]
    float* xp_wp[2]  = { wTs + 2 * (2 * kD * kH) + 2 * kD * kH,
                         wTs + 2 * (2 * kD * kH) + 2 * kD * kH + kD * kDBLP }; // [192][48]
    float* wEnd = wTs + 2 * (2 * kD * kH) + 2 * kD * kH + 2 * kD * kDBLP;
    float* R4 = wEnd;                             // kNM: xc0 (batched only)
    float* R5 = R4 + (size_t)kNM;                 // kNM: xc1 (batched only)
    size_t need_batched = (size_t)((R5 + (size_t)kNM) - ws) * sizeof(float);
    bool batched = (ws_size >= need_batched);

    const float* mw[2][8];
    for (int dir = 0; dir < 2; dir++) {
        int wi = 21 + dir * 9;
        mw[dir][0] = (const float*)d_in[wi + 1];  // conv_w
        mw[dir][1] = (const float*)d_in[wi + 2];  // conv_b
        mw[dir][2] = (const float*)d_in[wi + 4];  // dt_w
        mw[dir][3] = (const float*)d_in[wi + 5];  // dt_b
        mw[dir][4] = (const float*)d_in[wi + 6];  // A_log
        mw[dir][5] = (const float*)d_in[wi + 7];  // D
        transpose_kernel<<<(2 * kD * kH + 255) / 256, 256, 0, stream>>>(
            (const float*)d_in[wi + 0], in_wT[dir], 2 * kD, kH);
        transpose_kernel<<<(kH * kD + 255) / 256, 256, 0, stream>>>(
            (const float*)d_in[wi + 8], out_wp[dir], kH, kD);
        xppad_kernel<<<(kD * kDBLP + 255) / 256, 256, 0, stream>>>(
            (const float*)d_in[wi + 3], xp_wp[dir]);
    }

    int lnGrid = (kROWS + 3) / 4;
    dim3 fcGrid(kG, kT, kB);
    int gemmGrid = (kROWS + 63) / 64;
    int mcGrid = (kROWS * 48 + 255) / 256;

    // stage 1: x = x + fconv(x)
    ln_kernel<<<lnGrid, 256, 0, stream>>>(x, R1, ln1_g, ln1_b, kROWS);
    fconv_kernel<<<fcGrid, 256, 0, stream>>>(R1, x, xbuf, conv1_w, conv1_b, prelu1);

    // stage 2: x = x + full(x)   [lnf+squeeze fused; unsqueeze+ln2 fused]
    lnsq_kernel<<<lnGrid, 256, 0, stream>>>(xbuf, R2, lnf_g, lnf_b, sq_w, sq_b);
    fullmat_gemm<<<dim3(5, 4, kS), 256, 0, stream>>>(R2, R3, full_w, full_b);
    unsq_ln_kernel<<<lnGrid, 256, 0, stream>>>(R3, xbuf, unsq_w, unsq_b, ln2_g, ln2_b, R1);

    // stage 3: x = x + fconv(x)  (in-place: resid == out; R1 holds ln2 out)
    fconv_kernel<<<fcGrid, 256, 0, stream>>>(R1, xbuf, xbuf, conv2_w, conv2_b, prelu2);

    // mamba input: xn = LN(x)
    ln_kernel<<<lnGrid, 256, 0, stream>>>(xbuf, xn, lnm_g, lnm_b, kROWS);

    if (batched) {
        float* dbl0 = xn;                                  // xn dead after inprojs
        float* dbl1 = xn + (size_t)kROWS * kDBL;
        inproj_gemm<<<dim3(gemmGrid, 3), 256, 0, stream>>>(xn, in_wT[0], R1, R2);
        mconv_kernel<<<mcGrid, 256, 0, stream>>>(R1, R4, mw[0][0], mw[0][1], 0);
        inproj_gemm<<<dim3(gemmGrid, 3), 256, 0, stream>>>(xn, in_wT[1], R1, R3);
        mconv_kernel<<<mcGrid, 256, 0, stream>>>(R1, R5, mw[1][0], mw[1][1], 1);
        xpproj_gemm<<<gemmGrid, 256, 0, stream>>>(R4, dbl0, xp_wp[0]);
        xpproj_gemm<<<gemmGrid, 256, 0, stream>>>(R5, dbl1, xp_wp[1]);
        scan2_kernel<<<dim3(kBM, 2), 192, 0, stream>>>(
            dbl0, dbl1, R4, R5,
            mw[0][4], mw[1][4], mw[0][2], mw[1][2],
            mw[0][3], mw[1][3], mw[0][5], mw[1][5], 0);
        outproj_gemm<<<gemmGrid, 256, 0, stream>>>(R4, R2, out_wp[0], xbuf, (float*)d_out, 0);
        outproj_gemm<<<gemmGrid, 256, 0, stream>>>(R5, R3, out_wp[1], xbuf, (float*)d_out, 1);
    } else {
        for (int dir = 0; dir < 2; dir++) {
            inproj_gemm<<<dim3(gemmGrid, 3), 256, 0, stream>>>(xn, in_wT[dir], R1, R2);
            mconv_kernel<<<mcGrid, 256, 0, stream>>>(R1, R3, mw[dir][0], mw[dir][1], dir);
            xpproj_gemm<<<gemmGrid, 256, 0, stream>>>(R3, R1, xp_wp[dir]);
            scan2_kernel<<<dim3(kBM, 1), 192, 0, stream>>>(
                R1, R1, R3, R3,
                mw[dir][4], mw[dir][4], mw[dir][2], mw[dir][2],
                mw[dir][3], mw[dir][3], mw[dir][5], mw[dir][5], dir);
            outproj_gemm<<<gemmGrid, 256, 0, stream>>>(R3, R2, out_wp[dir], xbuf, (float*)d_out, dir);
        }
    }
}

// Round 16
// 876.433 us; speedup vs baseline: 1.0530x; 1.0210x over previous
//
#include <hip/hip_runtime.h>
#include <math.h>

// Problem constants
constexpr int kB   = 2;
constexpr int kF   = 257;   // FQ
constexpr int kT   = 100;
constexpr int kH   = 96;
constexpr int kS   = 8;
constexpr int kD   = 192;   // DIN
constexpr int kN   = 16;
constexpr int kR   = 6;
constexpr int kKF  = 5;
constexpr int kKM  = 4;
constexpr int kG   = 8;     // GROUPS
constexpr int kGC  = kH / kG;        // 12
constexpr int kBM  = kB * kF;        // 514
constexpr int kROWS = kB * kF * kT;  // 51400
constexpr int kNX  = kROWS * kH;     // 4,934,400
constexpr int kNM  = kROWS * kD;     // 9,868,800
constexpr int kDBL = kR + 2 * kN;    // 38
constexpr int kDBLP = 48;            // padded

__device__ inline float wave_reduce_sum(float v) {
    for (int o = 32; o > 0; o >>= 1) v += __shfl_xor(v, o, 64);
    return v;
}
__device__ inline float silu_f(float x) { return x / (1.f + __expf(-x)); }
__device__ inline float softplus_f(float x) { return x > 20.f ? x : log1pf(__expf(x)); }

// ---------------- LayerNorm over H=96, one wave per row ----------------
__global__ void ln_kernel(const float* __restrict__ in, float* __restrict__ out,
                          const float* __restrict__ g, const float* __restrict__ b,
                          int rows) {
    int wave = threadIdx.x >> 6;
    int lane = threadIdx.x & 63;
    int r = blockIdx.x * 4 + wave;
    if (r >= rows) return;
    const float* p = in + (size_t)r * kH;
    float v0 = p[lane];
    float v1 = (lane < 32) ? p[64 + lane] : 0.f;
    float s = wave_reduce_sum(v0 + v1);
    float mean = s * (1.f / 96.f);
    float d0 = v0 - mean;
    float d1 = (lane < 32) ? (v1 - mean) : 0.f;
    float vs = wave_reduce_sum(d0 * d0 + d1 * d1);
    float rstd = rsqrtf(vs * (1.f / 96.f) + 1e-5f);
    float* q = out + (size_t)r * kH;
    q[lane] = d0 * rstd * g[lane] + b[lane];
    if (lane < 32) q[64 + lane] = d1 * rstd * g[64 + lane] + b[64 + lane];
}

// ---------------- freq-conv stage ----------------
#define FDOT(S,K) \
  acc += xw[S][0].x*wr[K][0] + xw[S][0].y*wr[K][1] + xw[S][0].z*wr[K][2] + xw[S][0].w*wr[K][3] \
       + xw[S][1].x*wr[K][4] + xw[S][1].y*wr[K][5] + xw[S][1].z*wr[K][6] + xw[S][1].w*wr[K][7] \
       + xw[S][2].x*wr[K][8] + xw[S][2].y*wr[K][9] + xw[S][2].z*wr[K][10]+ xw[S][2].w*wr[K][11];

#define FSTEP(S0,S1,S2,S3,S4)                                              \
  if (f < fmax) {                                                          \
    const float4* cp = (const float4*)(Xs + (f + 4) * 12);                 \
    xw[S4][0] = cp[0]; xw[S4][1] = cp[1]; xw[S4][2] = cp[2];               \
    float acc = bias;                                                      \
    FDOT(S0,0) FDOT(S1,1) FDOT(S2,2) FDOT(S3,3) FDOT(S4,4)                 \
    float yv = acc > 0.f ? acc : alpha_h * acc;                            \
    size_t oi = ((size_t)(bb * kF + f) * kT + tt) * kH + g12 + hh;         \
    out[oi] = resid[oi] + yv;                                              \
    f++;                                                                   \
  }

__global__ __launch_bounds__(256)
void fconv_kernel(const float* __restrict__ ln, const float* __restrict__ resid,
                  float* __restrict__ out, const float* __restrict__ w,
                  const float* __restrict__ cb, const float* __restrict__ alpha) {
    __shared__ float Xs[261 * 12];
    __shared__ float Ws[kGC * kKF * 12];  // 720
    int g = blockIdx.x, tt = blockIdx.y, bb = blockIdx.z;
    int g12 = g * 12;
    int tid = threadIdx.x;

    for (int i = tid; i < 720; i += 256) Ws[i] = w[g * 720 + i];
    for (int i = tid; i < 257 * 12; i += 256) {
        int fs = i / 12, ci = i - fs * 12;
        Xs[(fs + 2) * 12 + ci] = ln[((size_t)(bb * kF + fs) * kT + tt) * kH + g12 + ci];
    }
    if (tid < 48) {
        const int padr[4] = {0, 1, 259, 260};
        Xs[padr[tid / 12] * 12 + (tid % 12)] = 0.f;
    }
    __syncthreads();

    int lane = tid & 63, wave = tid >> 6;
    int hh = lane % 12, fi = lane / 12;
    if (fi >= 5) return;                      // duplicate-slot lanes must retire (in-place race)
    int slot = wave * 5 + fi;
    int f0 = slot * 13;
    int fmax = min(f0 + 13, kF);

    float wr[5][12];
    #pragma unroll
    for (int k = 0; k < 5; k++)
        #pragma unroll
        for (int ci = 0; ci < 12; ci++)
            wr[k][ci] = Ws[hh * 60 + ci * 5 + k];

    float bias = cb[g12 + hh];
    float alpha_h = alpha[g12 + hh];

    float4 xw[5][3];
    #pragma unroll
    for (int s = 0; s < 4; s++) {
        int row = min(f0 + s, 260);
        const float4* cp = (const float4*)(Xs + row * 12);
        xw[s][0] = cp[0]; xw[s][1] = cp[1]; xw[s][2] = cp[2];
    }
    int f = f0;
    for (int rep = 0; rep < 3; rep++) {
        FSTEP(0,1,2,3,4)
        FSTEP(1,2,3,4,0)
        FSTEP(2,3,4,0,1)
        FSTEP(3,4,0,1,2)
        FSTEP(4,0,1,2,3)
    }
}

// ---------------- full stage: squeeze H->S with SiLU ----------------
__global__ void squeeze_kernel(const float* __restrict__ ln, float* __restrict__ s1,
                               const float* __restrict__ sqw, const float* __restrict__ sqb) {
    int bt = blockIdx.x;                       // b*kT + t
    int f = blockIdx.y * 64 + threadIdx.x;
    if (f >= kF) return;
    int b = bt / kT, t = bt % kT;
    const float* row = ln + ((size_t)(b * kF + f) * kT + t) * kH;
    float acc[kS];
    for (int s = 0; s < kS; s++) acc[s] = 0.f;
    for (int h = 0; h < kH; h++) {
        float v = row[h];
        for (int s = 0; s < kS; s++) acc[s] += v * sqw[s * kH + h];
    }
    for (int s = 0; s < kS; s++)
        s1[((size_t)bt * kS + s) * kF + f] = silu_f(acc[s] + sqb[s]);
}

// ---------------- full stage: per-group GEMM over F ----------------
__global__ __launch_bounds__(256)
void fullmat_gemm(const float* __restrict__ s1, float* __restrict__ s2,
                  const float* __restrict__ fw, const float* __restrict__ fb) {
    __shared__ float As[64 * 64];  // [fk][bt]
    __shared__ float Bs[64 * 64];  // [fk][k]
    int k0 = blockIdx.x * 64, bt0 = blockIdx.y * 64, g = blockIdx.z;
    int tid = threadIdx.x;
    int rt = tid >> 4, ct = tid & 15;
    float acc[4][4];
    #pragma unroll
    for (int i = 0; i < 4; i++)
        #pragma unroll
        for (int j = 0; j < 4; j++) acc[i][j] = 0.f;

    for (int f0 = 0; f0 < kF; f0 += 64) {
        int fcnt = min(64, kF - f0);
        for (int i = tid; i < 64 * 64; i += 256) {
            int m = i & 63, fk = i >> 6;
            int bt = bt0 + m, f = f0 + fk;
            As[fk * 64 + m] = (bt < kB * kT && f < kF)
                ? s1[((size_t)bt * kS + g) * kF + f] : 0.f;
            int k = k0 + m;
            Bs[fk * 64 + m] = (k < kF && f < kF)
                ? fw[(size_t)g * kF * kF + (size_t)k * kF + f] : 0.f;
        }
        __syncthreads();
        for (int f = 0; f < fcnt; f++) {
            float4 a4 = *(const float4*)&As[f * 64 + rt * 4];
            float4 b4 = *(const float4*)&Bs[f * 64 + ct * 4];
            float ar[4] = {a4.x, a4.y, a4.z, a4.w};
            float br[4] = {b4.x, b4.y, b4.z, b4.w};
            #pragma unroll
            for (int i = 0; i < 4; i++)
                #pragma unroll
                for (int j = 0; j < 4; j++) acc[i][j] += ar[i] * br[j];
        }
        __syncthreads();
    }
    #pragma unroll
    for (int i = 0; i < 4; i++) {
        int bt = bt0 + rt * 4 + i;
        if (bt >= kB * kT) continue;
        #pragma unroll
        for (int j = 0; j < 4; j++) {
            int k = k0 + ct * 4 + j;
            if (k >= kF) continue;
            s2[((size_t)bt * kS + g) * kF + k] = acc[i][j] + fb[g * kF + k];
        }
    }
}

// ---------------- full stage: unsqueeze S->H + SiLU + residual ----------------
__global__ void unsqueeze_kernel(const float* __restrict__ s2, float* __restrict__ x,
                                 const float* __restrict__ uw, const float* __restrict__ ub) {
    int idx = blockIdx.x * blockDim.x + threadIdx.x;
    if (idx >= kNX) return;
    int h = idx % kH;
    int t = (idx / kH) % kT;
    int f = (idx / (kH * kT)) % kF;
    int b = idx / (kH * kT * kF);
    int bt = b * kT + t;
    float acc = ub[h];
    for (int s = 0; s < kS; s++)
        acc += s2[((size_t)bt * kS + s) * kF + f] * uw[h * kS + s];
    x[idx] += silu_f(acc);
}

// ---------------- small weight transpose ----------------
__global__ void transpose_kernel(const float* __restrict__ in, float* __restrict__ out,
                                 int rows, int cols) {
    int idx = blockIdx.x * blockDim.x + threadIdx.x;
    if (idx >= rows * cols) return;
    int r = idx / cols, c = idx % cols;
    out[c * rows + r] = in[idx];
}

// xp_w [38][192] -> padded transpose wpx [192][48] (cols >=38 zero)
__global__ void xppad_kernel(const float* __restrict__ w, float* __restrict__ wp) {
    int i = blockIdx.x * 256 + threadIdx.x;
    if (i >= kD * kDBLP) return;
    int d = i / kDBLP, n = i % kDBLP;
    wp[i] = (n < kDBL) ? w[n * kD + d] : 0.f;
}

// ---------------- mamba in-proj GEMM: [51400x96] @ [96x384] ----------------
__global__ __launch_bounds__(256)
void inproj_gemm(const float* __restrict__ xn, const float* __restrict__ wT,
                 float* __restrict__ xin, float* __restrict__ z) {
    __shared__ float Al[64 * 96];  // 24.6 KB
    int r0 = blockIdx.x * 64;
    int c0 = blockIdx.y * 128;
    int tid = threadIdx.x;
    for (int i = tid; i < 64 * 24; i += 256) {
        int rr = i / 24, cq = i - rr * 24;
        int r = r0 + rr; if (r >= kROWS) r = kROWS - 1;
        *(float4*)&Al[rr * 96 + cq * 4] = *(const float4*)&xn[(size_t)r * kH + cq * 4];
    }
    __syncthreads();
    int rt = tid >> 5, ct = tid & 31;
    const float* ap = Al + rt * 8 * 96;
    const float* bp = wT + c0 + ct * 4;
    float4 acc[8];
    #pragma unroll
    for (int i = 0; i < 8; i++) acc[i] = make_float4(0.f, 0.f, 0.f, 0.f);
    for (int h = 0; h < 96; h++) {
        float4 b = *(const float4*)&bp[(size_t)h * 384];
        #pragma unroll
        for (int i = 0; i < 8; i++) {
            float av = ap[i * 96 + h];
            acc[i].x += av * b.x; acc[i].y += av * b.y;
            acc[i].z += av * b.z; acc[i].w += av * b.w;
        }
    }
    int cbase = c0 + ct * 4;
    #pragma unroll
    for (int i = 0; i < 8; i++) {
        int r = r0 + rt * 8 + i;
        if (r >= kROWS) break;
        if (cbase < kD) *(float4*)&xin[(size_t)r * kD + cbase] = acc[i];
        else            *(float4*)&z[(size_t)r * kD + cbase - kD] = acc[i];
    }
}

// ---------------- mamba out-proj GEMM + z-gating + combine ----------------
__global__ __launch_bounds__(256)
void outproj_gemm(const float* __restrict__ ym, const float* __restrict__ zg,
                  const float* __restrict__ wpT,
                  const float* __restrict__ xres, float* __restrict__ out, int dir) {
    __shared__ float Al[64 * 192];  // 49.2 KB
    int r0 = blockIdx.x * 64;
    int tid = threadIdx.x;
    for (int i = tid; i < 64 * 48; i += 256) {
        int rr = i / 48, cq = i - rr * 48;
        int r = r0 + rr; if (r >= kROWS) r = kROWS - 1;
        size_t gidx = (size_t)r * kD + cq * 4;
        float4 a = *(const float4*)&ym[gidx];
        float4 g4 = *(const float4*)&zg[gidx];
        a.x *= silu_f(g4.x); a.y *= silu_f(g4.y);
        a.z *= silu_f(g4.z); a.w *= silu_f(g4.w);
        *(float4*)&Al[rr * 192 + cq * 4] = a;
    }
    __syncthreads();
    int rt = tid >> 5, ct = tid & 31;   // cols 3*ct .. 3*ct+2
    const float* ap = Al + rt * 8 * 192;
    const float* bp = wpT + ct * 3;
    float acc[8][3];
    #pragma unroll
    for (int i = 0; i < 8; i++) { acc[i][0] = 0.f; acc[i][1] = 0.f; acc[i][2] = 0.f; }
    for (int h = 0; h < 192; h++) {
        float b0 = bp[h * 96], b1 = bp[h * 96 + 1], b2 = bp[h * 96 + 2];
        #pragma unroll
        for (int i = 0; i < 8; i++) {
            float av = ap[i * 192 + h];
            acc[i][0] += av * b0; acc[i][1] += av * b1; acc[i][2] += av * b2;
        }
    }
    int cbase = ct * 3;
    #pragma unroll
    for (int i = 0; i < 8; i++) {
        int r = r0 + rt * 8 + i;
        if (r >= kROWS) break;
        size_t o = (size_t)r * kH + cbase;
        #pragma unroll
        for (int j = 0; j < 3; j++) {
            float base = dir ? out[o + j] : xres[o + j];
            out[o + j] = base + 0.5f * acc[i][j];
        }
    }
}

// ---------------- mamba depthwise conv over T + SiLU ----------------
__global__ void mconv_kernel(const float* __restrict__ xin, float* __restrict__ xc,
                             const float* __restrict__ cw, const float* __restrict__ cb, int dir) {
    int qid = blockIdx.x * blockDim.x + threadIdx.x;
    if (qid >= kROWS * 48) return;
    int r = qid / 48, d4 = (qid - r * 48) * 4;
    int bm = r / kT, t = r - bm * kT;
    float4 acc = make_float4(cb[d4], cb[d4 + 1], cb[d4 + 2], cb[d4 + 3]);
    #pragma unroll
    for (int k = 0; k < kKM; k++) {
        int ts = dir ? (t + 3 - k) : (t + k - 3);
        if (ts < 0 || ts >= kT) continue;
        float4 v = *(const float4*)&xin[((size_t)bm * kT + ts) * kD + d4];
        acc.x += v.x * cw[(d4 + 0) * kKM + k];
        acc.y += v.y * cw[(d4 + 1) * kKM + k];
        acc.z += v.z * cw[(d4 + 2) * kKM + k];
        acc.w += v.w * cw[(d4 + 3) * kKM + k];
    }
    float4 o = make_float4(silu_f(acc.x), silu_f(acc.y), silu_f(acc.z), silu_f(acc.w));
    *(float4*)&xc[(size_t)r * kD + d4] = o;
}

// ---------------- mamba x-proj GEMM: [51400x192] @ [192x48pad] ----------------
__global__ __launch_bounds__(256)
void xpproj_gemm(const float* __restrict__ xc, float* __restrict__ dbl,
                 const float* __restrict__ wpx) {
    __shared__ float Al[64 * 192];  // 49.2 KB
    int r0 = blockIdx.x * 64;
    int tid = threadIdx.x;
    for (int i = tid; i < 64 * 48; i += 256) {
        int rr = i / 48, cq = i - rr * 48;
        int r = r0 + rr; if (r >= kROWS) r = kROWS - 1;
        *(float4*)&Al[rr * 192 + cq * 4] = *(const float4*)&xc[(size_t)r * kD + cq * 4];
    }
    __syncthreads();
    int rt = tid >> 5, ct = tid & 31;
    if (ct >= 24) return;               // 48 cols / 2 per thread
    const float* ap = Al + rt * 8 * 192;
    const float* bp = wpx + ct * 2;
    float acc[8][2];
    #pragma unroll
    for (int i = 0; i < 8; i++) { acc[i][0] = 0.f; acc[i][1] = 0.f; }
    for (int h = 0; h < 192; h++) {
        float b0 = bp[h * kDBLP], b1 = bp[h * kDBLP + 1];
        #pragma unroll
        for (int i = 0; i < 8; i++) {
            float av = ap[i * 192 + h];
            acc[i][0] += av * b0; acc[i][1] += av * b1;
        }
    }
    int cbase = ct * 2;
    #pragma unroll
    for (int i = 0; i < 8; i++) {
        int r = r0 + rt * 8 + i;
        if (r >= kROWS) break;
        #pragma unroll
        for (int j = 0; j < 2; j++) {
            int c = cbase + j;
            if (c < kDBL) dbl[(size_t)r * kDBL + c] = acc[i][j];
        }
    }
}

// ---------------- mamba selective scan (R13 proven body: __expf) ----------------
__global__ __launch_bounds__(192)
void scan2_kernel(const float* __restrict__ dbl0, const float* __restrict__ dbl1,
                  float* __restrict__ xc0, float* __restrict__ xc1,
                  const float* __restrict__ Al0, const float* __restrict__ Al1,
                  const float* __restrict__ dtw0, const float* __restrict__ dtw1,
                  const float* __restrict__ dtb0, const float* __restrict__ dtb1,
                  const float* __restrict__ Dp0, const float* __restrict__ Dp1,
                  int dirbase) {
    __shared__ float dsg[kT * 40];      // 16 KB
    int dd = blockIdx.y;
    int dir = dirbase + dd;
    const float* dbl   = dd ? dbl1 : dbl0;
    float* xcy         = dd ? xc1  : xc0;
    const float* A_log = dd ? Al1  : Al0;
    const float* dtw   = dd ? dtw1 : dtw0;
    const float* dtb   = dd ? dtb1 : dtb0;
    const float* Dp    = dd ? Dp1  : Dp0;

    int bm = blockIdx.x;
    int d = threadIdx.x;

    const float* drow = dbl + (size_t)bm * kT * kDBL;
    for (int i = d; i < kT * kDBL; i += 192) {
        int t = i / kDBL, j = i - t * kDBL;
        int slot = (j < 6) ? j : (j + 2);
        dsg[t * 40 + slot] = drow[i];
    }
    __syncthreads();

    float A[kN], h[kN], dw[kR];
    #pragma unroll
    for (int n = 0; n < kN; n++) { A[n] = -__expf(A_log[d * kN + n]); h[n] = 0.f; }
    #pragma unroll
    for (int j = 0; j < kR; j++) dw[j] = dtw[d * kR + j];
    float db = dtb[d], Dv = Dp[d];

    float* xrow = xcy + (size_t)bm * kT * kD + d;

    for (int tb = 0; tb < kT; tb += 4) {
        int ts[4];
        float xv[4];
        #pragma unroll
        for (int u = 0; u < 4; u++) {
            ts[u] = dir ? (kT - 1 - (tb + u)) : (tb + u);
            xv[u] = xrow[(size_t)ts[u] * kD];
        }
        #pragma unroll
        for (int u = 0; u < 4; u++) {
            const float* row = dsg + ts[u] * 40;
            float4 q0 = *(const float4*)(row);
            float4 q1 = *(const float4*)(row + 4);
            float s = db + q0.x * dw[0] + q0.y * dw[1] + q0.z * dw[2]
                         + q0.w * dw[3] + q1.x * dw[4] + q1.y * dw[5];
            float dt = softplus_f(s);
            float dtx = dt * xv[u];
            float4 B0 = *(const float4*)(row + 8);
            float4 B1 = *(const float4*)(row + 12);
            float4 B2 = *(const float4*)(row + 16);
            float4 B3 = *(const float4*)(row + 20);
            float4 C0 = *(const float4*)(row + 24);
            float4 C1 = *(const float4*)(row + 28);
            float4 C2 = *(const float4*)(row + 32);
            float4 C3 = *(const float4*)(row + 36);
            float y = 0.f;
            h[0]  = __expf(dt * A[0])  * h[0]  + dtx * B0.x;  y += h[0]  * C0.x;
            h[1]  = __expf(dt * A[1])  * h[1]  + dtx * B0.y;  y += h[1]  * C0.y;
            h[2]  = __expf(dt * A[2])  * h[2]  + dtx * B0.z;  y += h[2]  * C0.z;
            h[3]  = __expf(dt * A[3])  * h[3]  + dtx * B0.w;  y += h[3]  * C0.w;
            h[4]  = __expf(dt * A[4])  * h[4]  + dtx * B1.x;  y += h[4]  * C1.x;
            h[5]  = __expf(dt * A[5])  * h[5]  + dtx * B1.y;  y += h[5]  * C1.y;
            h[6]  = __expf(dt * A[6])  * h[6]  + dtx * B1.z;  y += h[6]  * C1.z;
            h[7]  = __expf(dt * A[7])  * h[7]  + dtx * B1.w;  y += h[7]  * C1.w;
            h[8]  = __expf(dt * A[8])  * h[8]  + dtx * B2.x;  y += h[8]  * C2.x;
            h[9]  = __expf(dt * A[9])  * h[9]  + dtx * B2.y;  y += h[9]  * C2.y;
            h[10] = __expf(dt * A[10]) * h[10] + dtx * B2.z;  y += h[10] * C2.z;
            h[11] = __expf(dt * A[11]) * h[11] + dtx * B2.w;  y += h[11] * C2.w;
            h[12] = __expf(dt * A[12]) * h[12] + dtx * B3.x;  y += h[12] * C3.x;
            h[13] = __expf(dt * A[13]) * h[13] + dtx * B3.y;  y += h[13] * C3.y;
            h[14] = __expf(dt * A[14]) * h[14] + dtx * B3.z;  y += h[14] * C3.z;
            h[15] = __expf(dt * A[15]) * h[15] + dtx * B3.w;  y += h[15] * C3.w;
            xrow[(size_t)ts[u] * kD] = y + xv[u] * Dv;
        }
    }
}

extern "C" void kernel_launch(void* const* d_in, const int* in_sizes, int n_in,
                              void* d_out, int out_size, void* d_ws, size_t ws_size,
                              hipStream_t stream) {
    const float* x       = (const float*)d_in[0];
    const float* ln1_g   = (const float*)d_in[1];
    const float* ln1_b   = (const float*)d_in[2];
    const float* conv1_w = (const float*)d_in[3];
    const float* conv1_b = (const float*)d_in[4];
    const float* prelu1  = (const float*)d_in[5];
    const float* lnf_g   = (const float*)d_in[6];
    const float* lnf_b   = (const float*)d_in[7];
    const float* sq_w    = (const float*)d_in[8];
    const float* sq_b    = (const float*)d_in[9];
    const float* full_w  = (const float*)d_in[10];
    const float* full_b  = (const float*)d_in[11];
    const float* unsq_w  = (const float*)d_in[12];
    const float* unsq_b  = (const float*)d_in[13];
    const float* ln2_g   = (const float*)d_in[14];
    const float* ln2_b   = (const float*)d_in[15];
    const float* conv2_w = (const float*)d_in[16];
    const float* conv2_b = (const float*)d_in[17];
    const float* prelu2  = (const float*)d_in[18];
    const float* lnm_g   = (const float*)d_in[19];
    const float* lnm_b   = (const float*)d_in[20];

    float* ws   = (float*)d_ws;
    float* xbuf = ws;
    float* xn   = ws + (size_t)kNX;
    float* R1   = xn + (size_t)kNX;               // kNM
    float* R2   = R1 + (size_t)kNM;               // kNM: s1 / z0
    float* R3   = R2 + (size_t)kNM;               // kNM: s2 / z1(batched) / xc(fallback)
    float* wTs  = R3 + (size_t)kNM;
    float* in_wT[2]  = { wTs, wTs + 2 * kD * kH };                  // [96][384]
    float* out_wp[2] = { wTs + 2 * (2 * kD * kH),
                         wTs + 2 * (2 * kD * kH) + kD * kH };       // [192][96]
    float* xp_wp[2]  = { wTs + 2 * (2 * kD * kH) + 2 * kD * kH,
                         wTs + 2 * (2 * kD * kH) + 2 * kD * kH + kD * kDBLP }; // [192][48]
    float* wEnd = wTs + 2 * (2 * kD * kH) + 2 * kD * kH + 2 * kD * kDBLP;
    float* R4 = wEnd;                             // kNM: xc0 (batched only)
    float* R5 = R4 + (size_t)kNM;                 // kNM: xc1 (batched only)
    size_t need_batched = (size_t)((R5 + (size_t)kNM) - ws) * sizeof(float);
    bool batched = (ws_size >= need_batched);

    const float* mw[2][8];
    for (int dir = 0; dir < 2; dir++) {
        int wi = 21 + dir * 9;
        mw[dir][0] = (const float*)d_in[wi + 1];  // conv_w
        mw[dir][1] = (const float*)d_in[wi + 2];  // conv_b
        mw[dir][2] = (const float*)d_in[wi + 4];  // dt_w
        mw[dir][3] = (const float*)d_in[wi + 5];  // dt_b
        mw[dir][4] = (const float*)d_in[wi + 6];  // A_log
        mw[dir][5] = (const float*)d_in[wi + 7];  // D
        transpose_kernel<<<(2 * kD * kH + 255) / 256, 256, 0, stream>>>(
            (const float*)d_in[wi + 0], in_wT[dir], 2 * kD, kH);
        transpose_kernel<<<(kH * kD + 255) / 256, 256, 0, stream>>>(
            (const float*)d_in[wi + 8], out_wp[dir], kH, kD);
        xppad_kernel<<<(kD * kDBLP + 255) / 256, 256, 0, stream>>>(
            (const float*)d_in[wi + 3], xp_wp[dir]);
    }

    int lnGrid = (kROWS + 3) / 4;
    int nxGrid = (kNX + 255) / 256;
    dim3 fcGrid(kG, kT, kB);
    int gemmGrid = (kROWS + 63) / 64;
    int mcGrid = (kROWS * 48 + 255) / 256;

    // stage 1: x = x + fconv(x)
    ln_kernel<<<lnGrid, 256, 0, stream>>>(x, R1, ln1_g, ln1_b, kROWS);
    fconv_kernel<<<fcGrid, 256, 0, stream>>>(R1, x, xbuf, conv1_w, conv1_b, prelu1);

    // stage 2: x = x + full(x)
    ln_kernel<<<lnGrid, 256, 0, stream>>>(xbuf, R1, lnf_g, lnf_b, kROWS);
    squeeze_kernel<<<dim3(kB * kT, (kF + 63) / 64), 64, 0, stream>>>(R1, R2, sq_w, sq_b);
    fullmat_gemm<<<dim3(5, 4, kS), 256, 0, stream>>>(R2, R3, full_w, full_b);
    unsqueeze_kernel<<<nxGrid, 256, 0, stream>>>(R3, xbuf, unsq_w, unsq_b);

    // stage 3: x = x + fconv(x)  (in-place: resid == out)
    ln_kernel<<<lnGrid, 256, 0, stream>>>(xbuf, R1, ln2_g, ln2_b, kROWS);
    fconv_kernel<<<fcGrid, 256, 0, stream>>>(R1, xbuf, xbuf, conv2_w, conv2_b, prelu2);

    // mamba input: xn = LN(x)
    ln_kernel<<<lnGrid, 256, 0, stream>>>(xbuf, xn, lnm_g, lnm_b, kROWS);

    if (batched) {
        float* dbl0 = xn;                                  // xn dead after inprojs
        float* dbl1 = xn + (size_t)kROWS * kDBL;
        inproj_gemm<<<dim3(gemmGrid, 3), 256, 0, stream>>>(xn, in_wT[0], R1, R2);
        mconv_kernel<<<mcGrid, 256, 0, stream>>>(R1, R4, mw[0][0], mw[0][1], 0);
        inproj_gemm<<<dim3(gemmGrid, 3), 256, 0, stream>>>(xn, in_wT[1], R1, R3);
        mconv_kernel<<<mcGrid, 256, 0, stream>>>(R1, R5, mw[1][0], mw[1][1], 1);
        xpproj_gemm<<<gemmGrid, 256, 0, stream>>>(R4, dbl0, xp_wp[0]);
        xpproj_gemm<<<gemmGrid, 256, 0, stream>>>(R5, dbl1, xp_wp[1]);
        scan2_kernel<<<dim3(kBM, 2), 192, 0, stream>>>(
            dbl0, dbl1, R4, R5,
            mw[0][4], mw[1][4], mw[0][2], mw[1][2],
            mw[0][3], mw[1][3], mw[0][5], mw[1][5], 0);
        outproj_gemm<<<gemmGrid, 256, 0, stream>>>(R4, R2, out_wp[0], xbuf, (float*)d_out, 0);
        outproj_gemm<<<gemmGrid, 256, 0, stream>>>(R5, R3, out_wp[1], xbuf, (float*)d_out, 1);
    } else {
        for (int dir = 0; dir < 2; dir++) {
            inproj_gemm<<<dim3(gemmGrid, 3), 256, 0, stream>>>(xn, in_wT[dir], R1, R2);
            mconv_kernel<<<mcGrid, 256, 0, stream>>>(R1, R3, mw[dir][0], mw[dir][1], dir);
            xpproj_gemm<<<gemmGrid, 256, 0, stream>>>(R3, R1, xp_wp[dir]);
            scan2_kernel<<<dim3(kBM, 1), 192, 0, stream>>>(
                R1, R1, R3, R3,
                mw[dir][4], mw[dir][4], mw[dir][2], mw[dir][2],
                mw[dir][3], mw[dir][3], mw[dir][5], mw[dir][5], dir);
            outproj_gemm<<<gemmGrid, 256, 0, stream>>>(R3, R2, out_wp[dir], xbuf, (float*)d_out, dir);
        }
    }
}